// Round 11
// baseline (312.519 us; speedup 1.0000x reference)
//
#include <hip/hip_runtime.h>

#define N_NODES 100000
#define N_EDGES 1600000
#define D 128
#define EPS 1e-5f

#define NPB_BITS 8
#define NODES_PER_BUCK 256
#define NBUCK ((N_NODES + NODES_PER_BUCK - 1) >> NPB_BITS)   // 391
#define BUCK_CAP 5120

#define CHUNK_E 8192
#define NB_BIN ((N_EDGES + CHUNK_E - 1) / CHUNK_E)           // 196

typedef unsigned int uint;
typedef unsigned short ushort;
using bf16x8 = __attribute__((ext_vector_type(8))) short;
using f32x4  = __attribute__((ext_vector_type(4))) float;

__device__ __forceinline__ ushort f2bf(float f) {
    uint u = __float_as_uint(f);
    return (ushort)((u + 0x7fffu + ((u >> 16) & 1u)) >> 16);   // RNE
}
__device__ __forceinline__ float bflo(uint u) { return __uint_as_float(u << 16); }
__device__ __forceinline__ float bfhi(uint u) { return __uint_as_float(u & 0xffff0000u); }

// ---------------- fused prep: bucket histogram + casts + bnprep ----------------
// blocks [0,256): edge-dst bucket histogram (grid-stride 256*256)
// [256,12756): x -> bf16 (3.2M ushort4)
// [12756,12884): w2_1   [12884,13012): w2_2   [13012,13076): w2_3
// 13076: bnprep both layers
#define PREP_GRID 13077
__global__ __launch_bounds__(256) void k_prep(
    const int* __restrict__ ei, int* __restrict__ bcnt,
    const float* __restrict__ x, ushort* __restrict__ xb,
    const float* __restrict__ wl1, const float* __restrict__ wr1, ushort* __restrict__ w21,
    const float* __restrict__ wl2, const float* __restrict__ wr2, ushort* __restrict__ w22,
    const float* __restrict__ wl3, const float* __restrict__ wr3, ushort* __restrict__ w23,
    const float* __restrict__ b1, const float* __restrict__ g1, const float* __restrict__ be1,
    const float* __restrict__ m1, const float* __restrict__ v1,
    float* __restrict__ bnA1, float* __restrict__ bnB1,
    const float* __restrict__ b2, const float* __restrict__ g2, const float* __restrict__ be2,
    const float* __restrict__ m2, const float* __restrict__ v2,
    float* __restrict__ bnA2, float* __restrict__ bnB2) {
    __shared__ int sc[NBUCK];
    int b = blockIdx.x, t = threadIdx.x;
    if (b < 256) {
        for (int i = t; i < NBUCK; i += 256) sc[i] = 0;
        __syncthreads();
        for (int e = b * 256 + t; e < N_EDGES; e += 256 * 256)
            atomicAdd(&sc[ei[N_EDGES + e] >> NPB_BITS], 1);
        __syncthreads();
        for (int i = t; i < NBUCK; i += 256) {
            int v = sc[i];
            if (v) atomicAdd(&bcnt[i], v);
        }
    } else if (b < 12756) {
        int i = (b - 256) * 256 + t;               // < 3.2M exactly
        float4 v = ((const float4*)x)[i];
        ushort4 o;
        o.x = f2bf(v.x); o.y = f2bf(v.y); o.z = f2bf(v.z); o.w = f2bf(v.w);
        ((ushort4*)xb)[i] = o;
    } else if (b < 12884) {
        int i = (b - 12756) * 256 + t;             // 128*256 = 32768 exactly
        int o = i >> 8, k = i & 255;
        w21[i] = f2bf((k < 128) ? wl1[o * 128 + k] : wr1[o * 128 + k - 128]);
    } else if (b < 13012) {
        int i = (b - 12884) * 256 + t;
        int o = i >> 8, k = i & 255;
        w22[i] = f2bf((k < 128) ? wl2[o * 128 + k] : wr2[o * 128 + k - 128]);
    } else if (b < 13076) {
        int i = (b - 13012) * 256 + t;             // 64*256 = 16384 exactly
        int o = i >> 7, k = i & 127;
        w23[i] = f2bf((o < 64) ? wl3[o * 128 + k] : wr3[(o - 64) * 128 + k]);
    } else {
        if (t < 128) {
            float a = g1[t] * rsqrtf(v1[t] + EPS);
            bnA1[t] = a; bnB1[t] = (b1[t] - m1[t]) * a + be1[t];
        } else {
            int c = t - 128;
            float a = g2[c] * rsqrtf(v2[c] + EPS);
            bnA2[c] = a; bnB2[c] = (b2[c] - m2[c]) * a + be2[c];
        }
    }
}

// ---------------- CSR: scan, bin, per-bucket build (unchanged from R10) ----------------

__global__ __launch_bounds__(1024) void k_bscan(const int* __restrict__ bcnt,
                                                int* __restrict__ bstart, int* __restrict__ bcur,
                                                int* __restrict__ row_start) {
    __shared__ int s[1024];
    int t = threadIdx.x;
    int own = (t < NBUCK) ? bcnt[t] : 0;
    s[t] = own;
    __syncthreads();
    for (int off = 1; off < 1024; off <<= 1) {
        int v = (t >= off) ? s[t - off] : 0;
        __syncthreads();
        s[t] += v;
        __syncthreads();
    }
    if (t < NBUCK) {
        int excl = s[t] - own;
        bstart[t] = excl;
        bcur[t] = excl;
    }
    if (t == 0) {
        bstart[NBUCK] = N_EDGES;
        row_start[N_NODES] = N_EDGES;
    }
}

// binning with LDS counting-sort: per chunk, sort edges by bucket in LDS,
// then write each bucket's run linearly (coalesced full-line writes).
__global__ __launch_bounds__(256) void k_bin2(const int* __restrict__ ei,
                                              int* __restrict__ bcur,
                                              uint* __restrict__ binned) {
    __shared__ int cnt[NBUCK];
    __shared__ int lbase[NBUCK];
    __shared__ int gbase[NBUCK];
    __shared__ int ssc[512];
    __shared__ uint sval[CHUNK_E];     // 32 KB
    __shared__ ushort sbkt[CHUNK_E];   // 16 KB
    int t = threadIdx.x;
    int e0 = blockIdx.x * CHUNK_E;
    int e1 = e0 + CHUNK_E; if (e1 > N_EDGES) e1 = N_EDGES;
    int ecnt = e1 - e0;
    for (int i = t; i < NBUCK; i += 256) cnt[i] = 0;
    __syncthreads();
    for (int e = e0 + t; e < e1; e += 256)
        atomicAdd(&cnt[ei[N_EDGES + e] >> NPB_BITS], 1);
    __syncthreads();
    // exclusive scan over NBUCK via 512-wide Hillis-Steele (2 elems/thread)
    int v0 = (t < NBUCK) ? cnt[t] : 0;
    int v1 = (t + 256 < NBUCK) ? cnt[t + 256] : 0;
    ssc[t] = v0; ssc[t + 256] = v1;
    __syncthreads();
    for (int off = 1; off < 512; off <<= 1) {
        int a0 = (t >= off) ? ssc[t - off] : 0;
        int a1 = (t + 256 >= off) ? ssc[t + 256 - off] : 0;
        __syncthreads();
        ssc[t] += a0; ssc[t + 256] += a1;
        __syncthreads();
    }
    if (t < NBUCK) lbase[t] = ssc[t] - v0;
    if (t + 256 < NBUCK) lbase[t + 256] = ssc[t + 256] - v1;
    __syncthreads();
    // reserve global ranges; reset cnt as local cursor
    for (int i = t; i < NBUCK; i += 256) {
        int v = cnt[i];
        gbase[i] = v ? atomicAdd(&bcur[i], v) : 0;
        cnt[i] = 0;
    }
    __syncthreads();
    // pass 2: scatter into LDS in bucket-sorted order
    for (int e = e0 + t; e < e1; e += 256) {
        int s = ei[e];
        int d = ei[N_EDGES + e];
        int b = d >> NPB_BITS;
        int pos = lbase[b] + atomicAdd(&cnt[b], 1);
        sval[pos] = ((uint)s << NPB_BITS) | (uint)(d & (NODES_PER_BUCK - 1));
        sbkt[pos] = (ushort)b;
    }
    __syncthreads();
    // linear coalesced write: consecutive slots of a run -> consecutive global
    for (int s = t; s < ecnt; s += 256) {
        int b = sbkt[s];
        binned[gbase[b] + (s - lbase[b])] = sval[s];
    }
}

// per-bucket local CSR; LDS-sorted then linear write of csr_src
__global__ __launch_bounds__(256) void k_bcsr(const uint* __restrict__ binned,
                                              const int* __restrict__ bstart,
                                              int* __restrict__ row_start,
                                              int* __restrict__ csr_src) {
    __shared__ int cnt[NODES_PER_BUCK];
    __shared__ int sc[NODES_PER_BUCK];
    __shared__ int cur[NODES_PER_BUCK];
    __shared__ uint ecache[BUCK_CAP];   // 20 KB
    __shared__ int sorted[BUCK_CAP];    // 20 KB
    int b = blockIdx.x, t = threadIdx.x;
    int s0 = bstart[b], s1 = bstart[b + 1];
    int m = s1 - s0;
    bool fits = (m <= BUCK_CAP);
    cnt[t] = 0;
    __syncthreads();
    for (int e = s0 + t; e < s1; e += 256) {
        uint u = binned[e];
        int idx = e - s0;
        if (idx < BUCK_CAP) ecache[idx] = u;
        atomicAdd(&cnt[u & (NODES_PER_BUCK - 1)], 1);
    }
    __syncthreads();
    int own = cnt[t];
    sc[t] = own;
    __syncthreads();
    for (int off = 1; off < NODES_PER_BUCK; off <<= 1) {
        int v = (t >= off) ? sc[t - off] : 0;
        __syncthreads();
        sc[t] += v;
        __syncthreads();
    }
    int lexcl = sc[t] - own;
    {
        int node = (b << NPB_BITS) + t;
        if (node < N_NODES) row_start[node] = s0 + lexcl;
        cur[t] = fits ? lexcl : (s0 + lexcl);
    }
    __syncthreads();
    if (fits) {
        for (int e = s0 + t; e < s1; e += 256) {
            uint u = ecache[e - s0];
            int pos = atomicAdd(&cur[u & (NODES_PER_BUCK - 1)], 1);
            sorted[pos] = (int)(u >> NPB_BITS);
        }
        __syncthreads();
        for (int s = t; s < m; s += 256)
            csr_src[s0 + s] = sorted[s];
    } else {
        for (int e = s0 + t; e < s1; e += 256) {
            uint u = (e - s0 < BUCK_CAP) ? ecache[e - s0] : binned[e];
            int pos = atomicAdd(&cur[u & (NODES_PER_BUCK - 1)], 1);
            csr_src[pos] = (int)(u >> NPB_BITS);
        }
    }
}

// ---------------- mean gather (R8 form: full row, 2 loads/lane in flight) ----------------
__global__ __launch_bounds__(256) void k_agg_mean(
    const ushort* __restrict__ Zin, const int* __restrict__ row_start,
    const int* __restrict__ csr_src, ushort* __restrict__ Agg) {
    int t = threadIdx.x;
    int w = t >> 6, l = t & 63;
    int n = blockIdx.x * 4 + w;
    int g = l >> 3, c = l & 7;
    int s0 = row_start[n], s1 = row_start[n + 1];
    float a[16];
#pragma unroll
    for (int j = 0; j < 16; ++j) a[j] = 0.f;
    for (int e = s0; e < s1; e += 8) {
        int ee = e + g;
        if (ee < s1) {
            int src = csr_src[ee];
            const ushort* zp = &Zin[(size_t)src * 128 + c * 16];
            uint4 v0 = *(const uint4*)zp;
            uint4 v1 = *(const uint4*)(zp + 8);
            a[0] += bflo(v0.x); a[1] += bfhi(v0.x);
            a[2] += bflo(v0.y); a[3] += bfhi(v0.y);
            a[4] += bflo(v0.z); a[5] += bfhi(v0.z);
            a[6] += bflo(v0.w); a[7] += bfhi(v0.w);
            a[8]  += bflo(v1.x); a[9]  += bfhi(v1.x);
            a[10] += bflo(v1.y); a[11] += bfhi(v1.y);
            a[12] += bflo(v1.z); a[13] += bfhi(v1.z);
            a[14] += bflo(v1.w); a[15] += bfhi(v1.w);
        }
    }
#pragma unroll
    for (int off = 8; off <= 32; off <<= 1)
#pragma unroll
        for (int j = 0; j < 16; ++j) a[j] += __shfl_xor(a[j], off);
    if (l < 8) {
        float inv = 1.f / fmaxf((float)(s1 - s0), 1.f);
        uint4 p0, p1;
        uint* q0 = (uint*)&p0;
        uint* q1 = (uint*)&p1;
#pragma unroll
        for (int j = 0; j < 4; ++j) {
            q0[j] = (uint)f2bf(a[2 * j] * inv)     | ((uint)f2bf(a[2 * j + 1] * inv) << 16);
            q1[j] = (uint)f2bf(a[8 + 2 * j] * inv) | ((uint)f2bf(a[9 + 2 * j] * inv) << 16);
        }
        ushort* op = &Agg[(size_t)n * 128 + l * 16];
        *(uint4*)op = p0;
        *(uint4*)(op + 8) = p1;
    }
}

// ---------------- MFMA GEMM layers 1/2 (unchanged) ----------------
__global__ __launch_bounds__(256) void k_gemm12(
    const ushort* __restrict__ Ag, const ushort* __restrict__ Xin,
    const ushort* __restrict__ W2,
    const float* __restrict__ bnA, const float* __restrict__ bnB,
    ushort* __restrict__ Hout) {
    __shared__ ushort sW[16384];   // 32 KB

    int t = threadIdx.x;
    int n0 = blockIdx.x * 64;
    int w = t >> 6, l = t & 63;

    int arow = n0 + 16 * w + (l & 15);
    if (arow >= N_NODES) arow = N_NODES - 1;
    int ko = (l >> 4) * 8;
    bf16x8 afr[8];
#pragma unroll
    for (int kt = 0; kt < 4; ++kt)
        afr[kt] = *(const bf16x8*)&Ag[(size_t)arow * 128 + kt * 32 + ko];
#pragma unroll
    for (int kt = 0; kt < 4; ++kt)
        afr[4 + kt] = *(const bf16x8*)&Xin[(size_t)arow * 128 + kt * 32 + ko];

    f32x4 acc[8];
#pragma unroll
    for (int ot = 0; ot < 8; ++ot) acc[ot] = (f32x4){0.f, 0.f, 0.f, 0.f};

#pragma unroll
    for (int p = 0; p < 2; ++p) {
        for (int s = t; s < 2048; s += 256) {
            int f = s >> 6, ln = s & 63;
            int o = (f >> 2) * 16 + (ln & 15);
            int k = p * 128 + (f & 3) * 32 + ((ln >> 4) * 8);
            *(uint4*)&sW[s * 8] = *(const uint4*)&W2[o * 256 + k];
        }
        __syncthreads();
#pragma unroll
        for (int ktl = 0; ktl < 4; ++ktl) {
            int kt = p * 4 + ktl;
#pragma unroll
            for (int ot = 0; ot < 8; ++ot) {
                bf16x8 bfr = *(const bf16x8*)&sW[((ot * 4 + ktl) * 64 + l) * 8];
                acc[ot] = __builtin_amdgcn_mfma_f32_16x16x32_bf16(afr[kt], bfr, acc[ot], 0, 0, 0);
            }
        }
        __syncthreads();
    }

    float* sC = (float*)sW;
    int r0 = (l >> 4) * 4;
#pragma unroll
    for (int ot = 0; ot < 8; ++ot)
#pragma unroll
        for (int j = 0; j < 4; ++j)
            sC[(16 * w + r0 + j) * 128 + ot * 16 + (l & 15)] = acc[ot][j];
    __syncthreads();

    for (int u = t; u < 1024; u += 256) {
        int r = u >> 4, cc = (u & 15) * 8;
        int n = n0 + r;
        if (n >= N_NODES) continue;
        float4 A0 = *(const float4*)&bnA[cc];
        float4 A1 = *(const float4*)&bnA[cc + 4];
        float4 B0 = *(const float4*)&bnB[cc];
        float4 B1 = *(const float4*)&bnB[cc + 4];
        const float* pa0 = (const float*)&A0;
        const float* pa1 = (const float*)&A1;
        const float* pb0 = (const float*)&B0;
        const float* pb1 = (const float*)&B1;
        uint4 pk;
        uint* pw = (uint*)&pk;
#pragma unroll
        for (int j = 0; j < 4; ++j) {
            int i0 = 2 * j, i1 = 2 * j + 1;
            float va = (i0 < 4) ? pa0[i0] : pa1[i0 - 4];
            float vb = (i0 < 4) ? pb0[i0] : pb1[i0 - 4];
            float wa = (i1 < 4) ? pa0[i1] : pa1[i1 - 4];
            float wb = (i1 < 4) ? pb0[i1] : pb1[i1 - 4];
            float h0 = fmaxf(sC[r * 128 + cc + i0] * va + vb, 0.f);
            float h1 = fmaxf(sC[r * 128 + cc + i1] * wa + wb, 0.f);
            pw[j] = (uint)f2bf(h0) | ((uint)f2bf(h1) << 16);
        }
        *(uint4*)&Hout[(size_t)n * 128 + cc] = pk;
    }
}

// ---------------- MFMA dual GEMM layer 3 (unchanged) ----------------
__global__ __launch_bounds__(256) void k_gemm3(
    const ushort* __restrict__ Xb, const ushort* __restrict__ W2,
    const float* __restrict__ bias,
    ushort* __restrict__ Zb, ushort* __restrict__ Yb) {
    constexpr int DOUT = 64;
    constexpr int NT = 128;
    constexpr int OT = 8;

    __shared__ ushort sW[OT * 4 * 64 * 8];   // 32 KB

    int t = threadIdx.x;
    int n0 = blockIdx.x * 64;
    int w = t >> 6, l = t & 63;
    int arow = n0 + 16 * w + (l & 15);
    if (arow >= N_NODES) arow = N_NODES - 1;
    const ushort* ap = &Xb[(size_t)arow * D + ((l >> 4) * 8)];
    bf16x8 afr[4];
#pragma unroll
    for (int kt = 0; kt < 4; ++kt) afr[kt] = *(const bf16x8*)(ap + kt * 32);

    for (int s = t; s < OT * 4 * 64; s += 256) {
        int f = s >> 6, ln = s & 63;
        int o = (f >> 2) * 16 + (ln & 15);
        int k = (f & 3) * 32 + ((ln >> 4) * 8);
        *(uint4*)&sW[s * 8] = *(const uint4*)&W2[o * D + k];
    }
    __syncthreads();

    f32x4 acc[OT];
#pragma unroll
    for (int ot = 0; ot < OT; ++ot) acc[ot] = (f32x4){0.f, 0.f, 0.f, 0.f};
#pragma unroll
    for (int kt = 0; kt < 4; ++kt)
#pragma unroll
        for (int ot = 0; ot < OT; ++ot) {
            bf16x8 bfr = *(const bf16x8*)&sW[((ot * 4 + kt) * 64 + l) * 8];
            acc[ot] = __builtin_amdgcn_mfma_f32_16x16x32_bf16(afr[kt], bfr, acc[ot], 0, 0, 0);
        }
    __syncthreads();

    float* sC = (float*)sW;
    int r0 = (l >> 4) * 4;
#pragma unroll
    for (int ot = 0; ot < OT; ++ot)
#pragma unroll
        for (int j = 0; j < 4; ++j)
            sC[(16 * w + r0 + j) * NT + ot * 16 + (l & 15)] = acc[ot][j];
    __syncthreads();

    constexpr int CH = NT / 8;
    for (int c = t; c < 64 * CH; c += 256) {
        int r = c / CH, cc = (c % CH) * 8;
        if (n0 + r >= N_NODES) continue;
        bool isY = cc >= DOUT;
        uint4 pk;
        uint* pw = (uint*)&pk;
#pragma unroll
        for (int j = 0; j < 4; ++j) {
            float f0 = sC[r * NT + cc + 2 * j];
            float f1 = sC[r * NT + cc + 2 * j + 1];
            if (isY) {
                f0 += bias[cc - DOUT + 2 * j];
                f1 += bias[cc - DOUT + 2 * j + 1];
            }
            pw[j] = (uint)f2bf(f0) | ((uint)f2bf(f1) << 16);
        }
        if (isY) *(uint4*)&Yb[(size_t)(n0 + r) * DOUT + cc - DOUT] = pk;
        else     *(uint4*)&Zb[(size_t)(n0 + r) * DOUT + cc] = pk;
    }
}

// ---------------- layer-3 aggregation (unchanged from R8) ----------------
__global__ __launch_bounds__(256) void k_agg3(
    const ushort* __restrict__ Zb, const int* __restrict__ row_start,
    const int* __restrict__ csr_src, const ushort* __restrict__ Yb,
    float* __restrict__ out) {
    int t = threadIdx.x;
    int w = t >> 6, l = t & 63;
    int n = blockIdx.x * 4 + w;
    int g = l >> 3, c = l & 7;
    int s0 = row_start[n], s1 = row_start[n + 1];
    float a[8];
#pragma unroll
    for (int j = 0; j < 8; ++j) a[j] = 0.f;
    for (int e = s0; e < s1; e += 16) {
        int e0 = e + g, e1 = e + g + 8;
        int src0 = (e0 < s1) ? csr_src[e0] : -1;
        int src1 = (e1 < s1) ? csr_src[e1] : -1;
        uint4 v0, v1;
        if (src0 >= 0) v0 = *(const uint4*)&Zb[(size_t)src0 * 64 + c * 8];
        if (src1 >= 0) v1 = *(const uint4*)&Zb[(size_t)src1 * 64 + c * 8];
        if (src0 >= 0) {
            a[0] += bflo(v0.x); a[1] += bfhi(v0.x);
            a[2] += bflo(v0.y); a[3] += bfhi(v0.y);
            a[4] += bflo(v0.z); a[5] += bfhi(v0.z);
            a[6] += bflo(v0.w); a[7] += bfhi(v0.w);
        }
        if (src1 >= 0) {
            a[0] += bflo(v1.x); a[1] += bfhi(v1.x);
            a[2] += bflo(v1.y); a[3] += bfhi(v1.y);
            a[4] += bflo(v1.z); a[5] += bfhi(v1.z);
            a[6] += bflo(v1.w); a[7] += bfhi(v1.w);
        }
    }
#pragma unroll
    for (int off = 8; off <= 32; off <<= 1)
#pragma unroll
        for (int j = 0; j < 8; ++j) a[j] += __shfl_xor(a[j], off);
    if (l < 8) {
        float inv = 1.f / fmaxf((float)(s1 - s0), 1.f);
        uint4 yv = *(const uint4*)&Yb[(size_t)n * 64 + l * 8];
        float4 o0, o1;
        o0.x = bflo(yv.x) + a[0] * inv; o0.y = bfhi(yv.x) + a[1] * inv;
        o0.z = bflo(yv.y) + a[2] * inv; o0.w = bfhi(yv.y) + a[3] * inv;
        o1.x = bflo(yv.z) + a[4] * inv; o1.y = bfhi(yv.z) + a[5] * inv;
        o1.z = bflo(yv.w) + a[6] * inv; o1.w = bfhi(yv.w) + a[7] * inv;
        float* po = &out[(size_t)n * 64 + l * 8];
        *(float4*)po = o0;
        *(float4*)(po + 4) = o1;
    }
}

// ---------------- launch ----------------

static inline size_t align256(size_t x) { return (x + 255) & ~(size_t)255; }

extern "C" void kernel_launch(void* const* d_in, const int* in_sizes, int n_in,
                              void* d_out, int out_size, void* d_ws, size_t ws_size,
                              hipStream_t stream) {
    const float* x    = (const float*)d_in[0];
    const int*   ei   = (const int*)d_in[1];      // int32 (JAX default int)
    const float* w_l1 = (const float*)d_in[2];
    const float* b_l1 = (const float*)d_in[3];
    const float* w_r1 = (const float*)d_in[4];
    const float* g1   = (const float*)d_in[5];
    const float* be1  = (const float*)d_in[6];
    const float* m1   = (const float*)d_in[7];
    const float* v1   = (const float*)d_in[8];
    const float* w_l2 = (const float*)d_in[9];
    const float* b_l2 = (const float*)d_in[10];
    const float* w_r2 = (const float*)d_in[11];
    const float* g2   = (const float*)d_in[12];
    const float* be2  = (const float*)d_in[13];
    const float* m2   = (const float*)d_in[14];
    const float* v2   = (const float*)d_in[15];
    const float* w_l3 = (const float*)d_in[16];
    const float* b_l3 = (const float*)d_in[17];
    const float* w_r3 = (const float*)d_in[18];
    float* out = (float*)d_out;

    char* w = (char*)d_ws;
    int* bcnt      = (int*)w;  w += align256((size_t)NBUCK * 4);
    int* bstart    = (int*)w;  w += align256((size_t)(NBUCK + 1) * 4);
    int* bcur      = (int*)w;  w += align256((size_t)NBUCK * 4);
    uint* binned   = (uint*)w; w += align256((size_t)N_EDGES * 4);
    int* row_start = (int*)w;  w += align256((size_t)(N_NODES + 1) * 4);
    int* csr_src   = (int*)w;  w += align256((size_t)N_EDGES * 4);
    ushort* xb     = (ushort*)w; w += align256((size_t)N_NODES * D * 2);
    ushort* ag     = (ushort*)w; w += align256((size_t)N_NODES * D * 2);
    ushort* h1     = (ushort*)w; w += align256((size_t)N_NODES * D * 2);
    ushort* h2     = (ushort*)w; w += align256((size_t)N_NODES * D * 2);
    ushort* Zb     = (ushort*)w; w += align256((size_t)N_NODES * 64 * 2);
    ushort* Yb     = (ushort*)w; w += align256((size_t)N_NODES * 64 * 2);
    ushort* w2_1   = (ushort*)w; w += align256((size_t)128 * 256 * 2);
    ushort* w2_2   = (ushort*)w; w += align256((size_t)128 * 256 * 2);
    ushort* w2_3   = (ushort*)w; w += align256((size_t)128 * 128 * 2);
    float* bnA1    = (float*)w;  w += align256(128 * 4);
    float* bnB1    = (float*)w;  w += align256(128 * 4);
    float* bnA2    = (float*)w;  w += align256(128 * 4);
    float* bnB2    = (float*)w;  w += align256(128 * 4);

    hipMemsetAsync(bcnt, 0, (size_t)NBUCK * 4, stream);

    // fused prep: bucket histogram + x/weight casts + bnprep (independent work
    // co-scheduled in one kernel; histogram latency hides under the streaming casts)
    k_prep<<<PREP_GRID, 256, 0, stream>>>(ei, bcnt, x, xb,
        w_l1, w_r1, w2_1, w_l2, w_r2, w2_2, w_l3, w_r3, w2_3,
        b_l1, g1, be1, m1, v1, bnA1, bnB1,
        b_l2, g2, be2, m2, v2, bnA2, bnB2);

    // CSR build
    k_bscan<<<1, 1024, 0, stream>>>(bcnt, bstart, bcur, row_start);
    k_bin2<<<NB_BIN, 256, 0, stream>>>(ei, bcur, binned);
    k_bcsr<<<NBUCK, 256, 0, stream>>>(binned, bstart, row_start, csr_src);

    int gb = (N_NODES + 63) / 64;       // 1563
    int ab = N_NODES / 4;               // 25000

    // layer 1: aggregate-first
    k_agg_mean<<<ab, 256, 0, stream>>>(xb, row_start, csr_src, ag);
    k_gemm12<<<gb, 256, 0, stream>>>(ag, xb, w2_1, bnA1, bnB1, h1);
    // layer 2
    k_agg_mean<<<ab, 256, 0, stream>>>(h1, row_start, csr_src, ag);
    k_gemm12<<<gb, 256, 0, stream>>>(ag, h1, w2_2, bnA2, bnB2, h2);
    // layer 3: GEMM then aggregate (Z rows are 128 B)
    k_gemm3<<<gb, 256, 0, stream>>>(h2, w2_3, b_l3, Zb, Yb);
    k_agg3<<<ab, 256, 0, stream>>>(Zb, row_start, csr_src, Yb, out);
}

// Round 12
// 300.392 us; speedup vs baseline: 1.0404x; 1.0404x over previous
//
#include <hip/hip_runtime.h>

#define N_NODES 100000
#define N_EDGES 1600000
#define D 128
#define EPS 1e-5f

#define NPB_BITS 8
#define NODES_PER_BUCK 256
#define NBUCK ((N_NODES + NODES_PER_BUCK - 1) >> NPB_BITS)   // 391
#define BUCK_CAP 5120

#define CHUNK_E 8192
#define NB_BIN ((N_EDGES + CHUNK_E - 1) / CHUNK_E)           // 196

typedef unsigned int uint;
typedef unsigned short ushort;
using bf16x8 = __attribute__((ext_vector_type(8))) short;
using f32x4  = __attribute__((ext_vector_type(4))) float;

__device__ __forceinline__ ushort f2bf(float f) {
    uint u = __float_as_uint(f);
    return (ushort)((u + 0x7fffu + ((u >> 16) & 1u)) >> 16);   // RNE
}
__device__ __forceinline__ float bflo(uint u) { return __uint_as_float(u << 16); }
__device__ __forceinline__ float bfhi(uint u) { return __uint_as_float(u & 0xffff0000u); }

// ---------------- fused prep: bucket histogram + casts + bnprep ----------------
#define PREP_GRID 13077
__global__ __launch_bounds__(256) void k_prep(
    const int* __restrict__ ei, int* __restrict__ bcnt,
    const float* __restrict__ x, ushort* __restrict__ xb,
    const float* __restrict__ wl1, const float* __restrict__ wr1, ushort* __restrict__ w21,
    const float* __restrict__ wl2, const float* __restrict__ wr2, ushort* __restrict__ w22,
    const float* __restrict__ wl3, const float* __restrict__ wr3, ushort* __restrict__ w23,
    const float* __restrict__ b1, const float* __restrict__ g1, const float* __restrict__ be1,
    const float* __restrict__ m1, const float* __restrict__ v1,
    float* __restrict__ bnA1, float* __restrict__ bnB1,
    const float* __restrict__ b2, const float* __restrict__ g2, const float* __restrict__ be2,
    const float* __restrict__ m2, const float* __restrict__ v2,
    float* __restrict__ bnA2, float* __restrict__ bnB2) {
    __shared__ int sc[NBUCK];
    int b = blockIdx.x, t = threadIdx.x;
    if (b < 256) {
        for (int i = t; i < NBUCK; i += 256) sc[i] = 0;
        __syncthreads();
        for (int e = b * 256 + t; e < N_EDGES; e += 256 * 256)
            atomicAdd(&sc[ei[N_EDGES + e] >> NPB_BITS], 1);
        __syncthreads();
        for (int i = t; i < NBUCK; i += 256) {
            int v = sc[i];
            if (v) atomicAdd(&bcnt[i], v);
        }
    } else if (b < 12756) {
        int i = (b - 256) * 256 + t;               // < 3.2M exactly
        float4 v = ((const float4*)x)[i];
        ushort4 o;
        o.x = f2bf(v.x); o.y = f2bf(v.y); o.z = f2bf(v.z); o.w = f2bf(v.w);
        ((ushort4*)xb)[i] = o;
    } else if (b < 12884) {
        int i = (b - 12756) * 256 + t;             // 128*256 = 32768 exactly
        int o = i >> 8, k = i & 255;
        w21[i] = f2bf((k < 128) ? wl1[o * 128 + k] : wr1[o * 128 + k - 128]);
    } else if (b < 13012) {
        int i = (b - 12884) * 256 + t;
        int o = i >> 8, k = i & 255;
        w22[i] = f2bf((k < 128) ? wl2[o * 128 + k] : wr2[o * 128 + k - 128]);
    } else if (b < 13076) {
        int i = (b - 13012) * 256 + t;             // 64*256 = 16384 exactly
        int o = i >> 7, k = i & 127;
        w23[i] = f2bf((o < 64) ? wl3[o * 128 + k] : wr3[(o - 64) * 128 + k]);
    } else {
        if (t < 128) {
            float a = g1[t] * rsqrtf(v1[t] + EPS);
            bnA1[t] = a; bnB1[t] = (b1[t] - m1[t]) * a + be1[t];
        } else {
            int c = t - 128;
            float a = g2[c] * rsqrtf(v2[c] + EPS);
            bnA2[c] = a; bnB2[c] = (b2[c] - m2[c]) * a + be2[c];
        }
    }
}

// ---------------- CSR: scan, bin, per-bucket build (unchanged) ----------------

__global__ __launch_bounds__(1024) void k_bscan(const int* __restrict__ bcnt,
                                                int* __restrict__ bstart, int* __restrict__ bcur,
                                                int* __restrict__ row_start) {
    __shared__ int s[1024];
    int t = threadIdx.x;
    int own = (t < NBUCK) ? bcnt[t] : 0;
    s[t] = own;
    __syncthreads();
    for (int off = 1; off < 1024; off <<= 1) {
        int v = (t >= off) ? s[t - off] : 0;
        __syncthreads();
        s[t] += v;
        __syncthreads();
    }
    if (t < NBUCK) {
        int excl = s[t] - own;
        bstart[t] = excl;
        bcur[t] = excl;
    }
    if (t == 0) {
        bstart[NBUCK] = N_EDGES;
        row_start[N_NODES] = N_EDGES;
    }
}

__global__ __launch_bounds__(256) void k_bin2(const int* __restrict__ ei,
                                              int* __restrict__ bcur,
                                              uint* __restrict__ binned) {
    __shared__ int cnt[NBUCK];
    __shared__ int lbase[NBUCK];
    __shared__ int gbase[NBUCK];
    __shared__ int ssc[512];
    __shared__ uint sval[CHUNK_E];     // 32 KB
    __shared__ ushort sbkt[CHUNK_E];   // 16 KB
    int t = threadIdx.x;
    int e0 = blockIdx.x * CHUNK_E;
    int e1 = e0 + CHUNK_E; if (e1 > N_EDGES) e1 = N_EDGES;
    int ecnt = e1 - e0;
    for (int i = t; i < NBUCK; i += 256) cnt[i] = 0;
    __syncthreads();
    for (int e = e0 + t; e < e1; e += 256)
        atomicAdd(&cnt[ei[N_EDGES + e] >> NPB_BITS], 1);
    __syncthreads();
    int v0 = (t < NBUCK) ? cnt[t] : 0;
    int v1 = (t + 256 < NBUCK) ? cnt[t + 256] : 0;
    ssc[t] = v0; ssc[t + 256] = v1;
    __syncthreads();
    for (int off = 1; off < 512; off <<= 1) {
        int a0 = (t >= off) ? ssc[t - off] : 0;
        int a1 = (t + 256 >= off) ? ssc[t + 256 - off] : 0;
        __syncthreads();
        ssc[t] += a0; ssc[t + 256] += a1;
        __syncthreads();
    }
    if (t < NBUCK) lbase[t] = ssc[t] - v0;
    if (t + 256 < NBUCK) lbase[t + 256] = ssc[t + 256] - v1;
    __syncthreads();
    for (int i = t; i < NBUCK; i += 256) {
        int v = cnt[i];
        gbase[i] = v ? atomicAdd(&bcur[i], v) : 0;
        cnt[i] = 0;
    }
    __syncthreads();
    for (int e = e0 + t; e < e1; e += 256) {
        int s = ei[e];
        int d = ei[N_EDGES + e];
        int b = d >> NPB_BITS;
        int pos = lbase[b] + atomicAdd(&cnt[b], 1);
        sval[pos] = ((uint)s << NPB_BITS) | (uint)(d & (NODES_PER_BUCK - 1));
        sbkt[pos] = (ushort)b;
    }
    __syncthreads();
    for (int s = t; s < ecnt; s += 256) {
        int b = sbkt[s];
        binned[gbase[b] + (s - lbase[b])] = sval[s];
    }
}

__global__ __launch_bounds__(256) void k_bcsr(const uint* __restrict__ binned,
                                              const int* __restrict__ bstart,
                                              int* __restrict__ row_start,
                                              int* __restrict__ csr_src) {
    __shared__ int cnt[NODES_PER_BUCK];
    __shared__ int sc[NODES_PER_BUCK];
    __shared__ int cur[NODES_PER_BUCK];
    __shared__ uint ecache[BUCK_CAP];   // 20 KB
    __shared__ int sorted[BUCK_CAP];    // 20 KB
    int b = blockIdx.x, t = threadIdx.x;
    int s0 = bstart[b], s1 = bstart[b + 1];
    int m = s1 - s0;
    bool fits = (m <= BUCK_CAP);
    cnt[t] = 0;
    __syncthreads();
    for (int e = s0 + t; e < s1; e += 256) {
        uint u = binned[e];
        int idx = e - s0;
        if (idx < BUCK_CAP) ecache[idx] = u;
        atomicAdd(&cnt[u & (NODES_PER_BUCK - 1)], 1);
    }
    __syncthreads();
    int own = cnt[t];
    sc[t] = own;
    __syncthreads();
    for (int off = 1; off < NODES_PER_BUCK; off <<= 1) {
        int v = (t >= off) ? sc[t - off] : 0;
        __syncthreads();
        sc[t] += v;
        __syncthreads();
    }
    int lexcl = sc[t] - own;
    {
        int node = (b << NPB_BITS) + t;
        if (node < N_NODES) row_start[node] = s0 + lexcl;
        cur[t] = fits ? lexcl : (s0 + lexcl);
    }
    __syncthreads();
    if (fits) {
        for (int e = s0 + t; e < s1; e += 256) {
            uint u = ecache[e - s0];
            int pos = atomicAdd(&cur[u & (NODES_PER_BUCK - 1)], 1);
            sorted[pos] = (int)(u >> NPB_BITS);
        }
        __syncthreads();
        for (int s = t; s < m; s += 256)
            csr_src[s0 + s] = sorted[s];
    } else {
        for (int e = s0 + t; e < s1; e += 256) {
            uint u = (e - s0 < BUCK_CAP) ? ecache[e - s0] : binned[e];
            int pos = atomicAdd(&cur[u & (NODES_PER_BUCK - 1)], 1);
            csr_src[pos] = (int)(u >> NPB_BITS);
        }
    }
}

// ---------------- mean gather (R8 form, unchanged) ----------------
__global__ __launch_bounds__(256) void k_agg_mean(
    const ushort* __restrict__ Zin, const int* __restrict__ row_start,
    const int* __restrict__ csr_src, ushort* __restrict__ Agg) {
    int t = threadIdx.x;
    int w = t >> 6, l = t & 63;
    int n = blockIdx.x * 4 + w;
    int g = l >> 3, c = l & 7;
    int s0 = row_start[n], s1 = row_start[n + 1];
    float a[16];
#pragma unroll
    for (int j = 0; j < 16; ++j) a[j] = 0.f;
    for (int e = s0; e < s1; e += 8) {
        int ee = e + g;
        if (ee < s1) {
            int src = csr_src[ee];
            const ushort* zp = &Zin[(size_t)src * 128 + c * 16];
            uint4 v0 = *(const uint4*)zp;
            uint4 v1 = *(const uint4*)(zp + 8);
            a[0] += bflo(v0.x); a[1] += bfhi(v0.x);
            a[2] += bflo(v0.y); a[3] += bfhi(v0.y);
            a[4] += bflo(v0.z); a[5] += bfhi(v0.z);
            a[6] += bflo(v0.w); a[7] += bfhi(v0.w);
            a[8]  += bflo(v1.x); a[9]  += bfhi(v1.x);
            a[10] += bflo(v1.y); a[11] += bfhi(v1.y);
            a[12] += bflo(v1.z); a[13] += bfhi(v1.z);
            a[14] += bflo(v1.w); a[15] += bfhi(v1.w);
        }
    }
#pragma unroll
    for (int off = 8; off <= 32; off <<= 1)
#pragma unroll
        for (int j = 0; j < 16; ++j) a[j] += __shfl_xor(a[j], off);
    if (l < 8) {
        float inv = 1.f / fmaxf((float)(s1 - s0), 1.f);
        uint4 p0, p1;
        uint* q0 = (uint*)&p0;
        uint* q1 = (uint*)&p1;
#pragma unroll
        for (int j = 0; j < 4; ++j) {
            q0[j] = (uint)f2bf(a[2 * j] * inv)     | ((uint)f2bf(a[2 * j + 1] * inv) << 16);
            q1[j] = (uint)f2bf(a[8 + 2 * j] * inv) | ((uint)f2bf(a[9 + 2 * j] * inv) << 16);
        }
        ushort* op = &Agg[(size_t)n * 128 + l * 16];
        *(uint4*)op = p0;
        *(uint4*)(op + 8) = p1;
    }
}

// ---------------- MFMA GEMM layer 1 (unchanged gemm12) ----------------
__global__ __launch_bounds__(256) void k_gemm12(
    const ushort* __restrict__ Ag, const ushort* __restrict__ Xin,
    const ushort* __restrict__ W2,
    const float* __restrict__ bnA, const float* __restrict__ bnB,
    ushort* __restrict__ Hout) {
    __shared__ ushort sW[16384];   // 32 KB

    int t = threadIdx.x;
    int n0 = blockIdx.x * 64;
    int w = t >> 6, l = t & 63;

    int arow = n0 + 16 * w + (l & 15);
    if (arow >= N_NODES) arow = N_NODES - 1;
    int ko = (l >> 4) * 8;
    bf16x8 afr[8];
#pragma unroll
    for (int kt = 0; kt < 4; ++kt)
        afr[kt] = *(const bf16x8*)&Ag[(size_t)arow * 128 + kt * 32 + ko];
#pragma unroll
    for (int kt = 0; kt < 4; ++kt)
        afr[4 + kt] = *(const bf16x8*)&Xin[(size_t)arow * 128 + kt * 32 + ko];

    f32x4 acc[8];
#pragma unroll
    for (int ot = 0; ot < 8; ++ot) acc[ot] = (f32x4){0.f, 0.f, 0.f, 0.f};

#pragma unroll
    for (int p = 0; p < 2; ++p) {
        for (int s = t; s < 2048; s += 256) {
            int f = s >> 6, ln = s & 63;
            int o = (f >> 2) * 16 + (ln & 15);
            int k = p * 128 + (f & 3) * 32 + ((ln >> 4) * 8);
            *(uint4*)&sW[s * 8] = *(const uint4*)&W2[o * 256 + k];
        }
        __syncthreads();
#pragma unroll
        for (int ktl = 0; ktl < 4; ++ktl) {
            int kt = p * 4 + ktl;
#pragma unroll
            for (int ot = 0; ot < 8; ++ot) {
                bf16x8 bfr = *(const bf16x8*)&sW[((ot * 4 + ktl) * 64 + l) * 8];
                acc[ot] = __builtin_amdgcn_mfma_f32_16x16x32_bf16(afr[kt], bfr, acc[ot], 0, 0, 0);
            }
        }
        __syncthreads();
    }

    float* sC = (float*)sW;
    int r0 = (l >> 4) * 4;
#pragma unroll
    for (int ot = 0; ot < 8; ++ot)
#pragma unroll
        for (int j = 0; j < 4; ++j)
            sC[(16 * w + r0 + j) * 128 + ot * 16 + (l & 15)] = acc[ot][j];
    __syncthreads();

    for (int u = t; u < 1024; u += 256) {
        int r = u >> 4, cc = (u & 15) * 8;
        int n = n0 + r;
        if (n >= N_NODES) continue;
        uint4 pk;
        uint* pw = (uint*)&pk;
#pragma unroll
        for (int j = 0; j < 4; ++j) {
            int i0 = cc + 2 * j, i1 = cc + 2 * j + 1;
            float h0 = fmaxf(sC[r * 128 + i0] * bnA[i0] + bnB[i0], 0.f);
            float h1 = fmaxf(sC[r * 128 + i1] * bnA[i1] + bnB[i1], 0.f);
            pw[j] = (uint)f2bf(h0) | ((uint)f2bf(h1) << 16);
        }
        *(uint4*)&Hout[(size_t)n * 128 + cc] = pk;
    }
}

// ---------------- fused layer-2 GEMM + layer-3 dual GEMM ----------------
// Phase A: h2 = relu(bnA*(Ag@Wl2^T + H1@Wr2^T) + bnB) computed into LDS (bf16,
//          padded stride 136 to break bank conflicts on fragment re-read).
// Phase B: Z3 = h2@Wl3^T -> Zb, Y3 = h2@Wr3^T + b3 -> Yb, A-operand from LDS.
// h2 never touches global memory (saves 51 MB round-trip + one launch).
__global__ __launch_bounds__(256) void k_gemm2f(
    const ushort* __restrict__ Ag, const ushort* __restrict__ Xin,
    const ushort* __restrict__ W2,
    const float* __restrict__ bnA, const float* __restrict__ bnB,
    const ushort* __restrict__ W3, const float* __restrict__ bias3,
    ushort* __restrict__ Zb, ushort* __restrict__ Yb) {
    __shared__ ushort sW[16384];       // 32 KB: W2/W3 staging, reused as f32 sC[64][128]
    __shared__ ushort sH[64 * 136];    // 17 KB: h2 tile, padded

    int t = threadIdx.x;
    int n0 = blockIdx.x * 64;
    int w = t >> 6, l = t & 63;
    int ko = (l >> 4) * 8;
    int r0 = (l >> 4) * 4;

    // ---- phase A: layer-2 dual GEMM ----
    int arow = n0 + 16 * w + (l & 15);
    if (arow >= N_NODES) arow = N_NODES - 1;
    bf16x8 afr[8];
#pragma unroll
    for (int kt = 0; kt < 4; ++kt)
        afr[kt] = *(const bf16x8*)&Ag[(size_t)arow * 128 + kt * 32 + ko];
#pragma unroll
    for (int kt = 0; kt < 4; ++kt)
        afr[4 + kt] = *(const bf16x8*)&Xin[(size_t)arow * 128 + kt * 32 + ko];

    f32x4 acc[8];
#pragma unroll
    for (int ot = 0; ot < 8; ++ot) acc[ot] = (f32x4){0.f, 0.f, 0.f, 0.f};

#pragma unroll
    for (int p = 0; p < 2; ++p) {
        for (int s = t; s < 2048; s += 256) {
            int f = s >> 6, ln = s & 63;
            int o = (f >> 2) * 16 + (ln & 15);
            int k = p * 128 + (f & 3) * 32 + ((ln >> 4) * 8);
            *(uint4*)&sW[s * 8] = *(const uint4*)&W2[o * 256 + k];
        }
        __syncthreads();
#pragma unroll
        for (int ktl = 0; ktl < 4; ++ktl) {
            int kt = p * 4 + ktl;
#pragma unroll
            for (int ot = 0; ot < 8; ++ot) {
                bf16x8 bfr = *(const bf16x8*)&sW[((ot * 4 + ktl) * 64 + l) * 8];
                acc[ot] = __builtin_amdgcn_mfma_f32_16x16x32_bf16(afr[kt], bfr, acc[ot], 0, 0, 0);
            }
        }
        __syncthreads();
    }

    float* sC = (float*)sW;
#pragma unroll
    for (int ot = 0; ot < 8; ++ot)
#pragma unroll
        for (int j = 0; j < 4; ++j)
            sC[(16 * w + r0 + j) * 128 + ot * 16 + (l & 15)] = acc[ot][j];
    __syncthreads();

    // BN+ReLU -> h2 bf16 into sH (stride 136)
    for (int u = t; u < 1024; u += 256) {
        int r = u >> 4, cc = (u & 15) * 8;
        uint4 pk;
        uint* pw = (uint*)&pk;
#pragma unroll
        for (int j = 0; j < 4; ++j) {
            int i0 = cc + 2 * j, i1 = cc + 2 * j + 1;
            float h0 = fmaxf(sC[r * 128 + i0] * bnA[i0] + bnB[i0], 0.f);
            float h1 = fmaxf(sC[r * 128 + i1] * bnA[i1] + bnB[i1], 0.f);
            pw[j] = (uint)f2bf(h0) | ((uint)f2bf(h1) << 16);
        }
        *(uint4*)&sH[r * 136 + cc] = pk;
    }
    __syncthreads();

    // ---- phase B: layer-3 dual GEMM from LDS ----
    int hrow = 16 * w + (l & 15);
    bf16x8 a3[4];
#pragma unroll
    for (int kt = 0; kt < 4; ++kt)
        a3[kt] = *(const bf16x8*)&sH[hrow * 136 + kt * 32 + ko];

    // stage W3 [128 out][128 k] in fragment order (sC is dead now)
    for (int s = t; s < 2048; s += 256) {
        int f = s >> 6, ln = s & 63;
        int o = (f >> 2) * 16 + (ln & 15);
        int k = (f & 3) * 32 + ((ln >> 4) * 8);
        *(uint4*)&sW[s * 8] = *(const uint4*)&W3[o * 128 + k];
    }
    __syncthreads();

    f32x4 acc3[8];
#pragma unroll
    for (int ot = 0; ot < 8; ++ot) acc3[ot] = (f32x4){0.f, 0.f, 0.f, 0.f};
#pragma unroll
    for (int kt = 0; kt < 4; ++kt)
#pragma unroll
        for (int ot = 0; ot < 8; ++ot) {
            bf16x8 bfr = *(const bf16x8*)&sW[((ot * 4 + kt) * 64 + l) * 8];
            acc3[ot] = __builtin_amdgcn_mfma_f32_16x16x32_bf16(a3[kt], bfr, acc3[ot], 0, 0, 0);
        }
    __syncthreads();   // all waves done reading W3 before overwrite

#pragma unroll
    for (int ot = 0; ot < 8; ++ot)
#pragma unroll
        for (int j = 0; j < 4; ++j)
            sC[(16 * w + r0 + j) * 128 + ot * 16 + (l & 15)] = acc3[ot][j];
    __syncthreads();

    // epilogue: Z cols [0,64) -> Zb, Y cols [64,128)+bias -> Yb
    for (int c = t; c < 64 * 16; c += 256) {
        int r = c >> 4, cc = (c & 15) * 8;
        if (n0 + r >= N_NODES) continue;
        bool isY = cc >= 64;
        uint4 pk;
        uint* pw = (uint*)&pk;
#pragma unroll
        for (int j = 0; j < 4; ++j) {
            float f0 = sC[r * 128 + cc + 2 * j];
            float f1 = sC[r * 128 + cc + 2 * j + 1];
            if (isY) {
                f0 += bias3[cc - 64 + 2 * j];
                f1 += bias3[cc - 64 + 2 * j + 1];
            }
            pw[j] = (uint)f2bf(f0) | ((uint)f2bf(f1) << 16);
        }
        if (isY) *(uint4*)&Yb[(size_t)(n0 + r) * 64 + cc - 64] = pk;
        else     *(uint4*)&Zb[(size_t)(n0 + r) * 64 + cc] = pk;
    }
}

// ---------------- layer-3 aggregation (unchanged from R8) ----------------
__global__ __launch_bounds__(256) void k_agg3(
    const ushort* __restrict__ Zb, const int* __restrict__ row_start,
    const int* __restrict__ csr_src, const ushort* __restrict__ Yb,
    float* __restrict__ out) {
    int t = threadIdx.x;
    int w = t >> 6, l = t & 63;
    int n = blockIdx.x * 4 + w;
    int g = l >> 3, c = l & 7;
    int s0 = row_start[n], s1 = row_start[n + 1];
    float a[8];
#pragma unroll
    for (int j = 0; j < 8; ++j) a[j] = 0.f;
    for (int e = s0; e < s1; e += 16) {
        int e0 = e + g, e1 = e + g + 8;
        int src0 = (e0 < s1) ? csr_src[e0] : -1;
        int src1 = (e1 < s1) ? csr_src[e1] : -1;
        uint4 v0, v1;
        if (src0 >= 0) v0 = *(const uint4*)&Zb[(size_t)src0 * 64 + c * 8];
        if (src1 >= 0) v1 = *(const uint4*)&Zb[(size_t)src1 * 64 + c * 8];
        if (src0 >= 0) {
            a[0] += bflo(v0.x); a[1] += bfhi(v0.x);
            a[2] += bflo(v0.y); a[3] += bfhi(v0.y);
            a[4] += bflo(v0.z); a[5] += bfhi(v0.z);
            a[6] += bflo(v0.w); a[7] += bfhi(v0.w);
        }
        if (src1 >= 0) {
            a[0] += bflo(v1.x); a[1] += bfhi(v1.x);
            a[2] += bflo(v1.y); a[3] += bfhi(v1.y);
            a[4] += bflo(v1.z); a[5] += bfhi(v1.z);
            a[6] += bflo(v1.w); a[7] += bfhi(v1.w);
        }
    }
#pragma unroll
    for (int off = 8; off <= 32; off <<= 1)
#pragma unroll
        for (int j = 0; j < 8; ++j) a[j] += __shfl_xor(a[j], off);
    if (l < 8) {
        float inv = 1.f / fmaxf((float)(s1 - s0), 1.f);
        uint4 yv = *(const uint4*)&Yb[(size_t)n * 64 + l * 8];
        float4 o0, o1;
        o0.x = bflo(yv.x) + a[0] * inv; o0.y = bfhi(yv.x) + a[1] * inv;
        o0.z = bflo(yv.y) + a[2] * inv; o0.w = bfhi(yv.y) + a[3] * inv;
        o1.x = bflo(yv.z) + a[4] * inv; o1.y = bfhi(yv.z) + a[5] * inv;
        o1.z = bflo(yv.w) + a[6] * inv; o1.w = bfhi(yv.w) + a[7] * inv;
        float* po = &out[(size_t)n * 64 + l * 8];
        *(float4*)po = o0;
        *(float4*)(po + 4) = o1;
    }
}

// ---------------- launch ----------------

static inline size_t align256(size_t x) { return (x + 255) & ~(size_t)255; }

extern "C" void kernel_launch(void* const* d_in, const int* in_sizes, int n_in,
                              void* d_out, int out_size, void* d_ws, size_t ws_size,
                              hipStream_t stream) {
    const float* x    = (const float*)d_in[0];
    const int*   ei   = (const int*)d_in[1];      // int32 (JAX default int)
    const float* w_l1 = (const float*)d_in[2];
    const float* b_l1 = (const float*)d_in[3];
    const float* w_r1 = (const float*)d_in[4];
    const float* g1   = (const float*)d_in[5];
    const float* be1  = (const float*)d_in[6];
    const float* m1   = (const float*)d_in[7];
    const float* v1   = (const float*)d_in[8];
    const float* w_l2 = (const float*)d_in[9];
    const float* b_l2 = (const float*)d_in[10];
    const float* w_r2 = (const float*)d_in[11];
    const float* g2   = (const float*)d_in[12];
    const float* be2  = (const float*)d_in[13];
    const float* m2   = (const float*)d_in[14];
    const float* v2   = (const float*)d_in[15];
    const float* w_l3 = (const float*)d_in[16];
    const float* b_l3 = (const float*)d_in[17];
    const float* w_r3 = (const float*)d_in[18];
    float* out = (float*)d_out;

    char* w = (char*)d_ws;
    int* bcnt      = (int*)w;  w += align256((size_t)NBUCK * 4);
    int* bstart    = (int*)w;  w += align256((size_t)(NBUCK + 1) * 4);
    int* bcur      = (int*)w;  w += align256((size_t)NBUCK * 4);
    uint* binned   = (uint*)w; w += align256((size_t)N_EDGES * 4);
    int* row_start = (int*)w;  w += align256((size_t)(N_NODES + 1) * 4);
    int* csr_src   = (int*)w;  w += align256((size_t)N_EDGES * 4);
    ushort* xb     = (ushort*)w; w += align256((size_t)N_NODES * D * 2);
    ushort* ag     = (ushort*)w; w += align256((size_t)N_NODES * D * 2);
    ushort* h1     = (ushort*)w; w += align256((size_t)N_NODES * D * 2);
    ushort* Zb     = (ushort*)w; w += align256((size_t)N_NODES * 64 * 2);
    ushort* Yb     = (ushort*)w; w += align256((size_t)N_NODES * 64 * 2);
    ushort* w2_1   = (ushort*)w; w += align256((size_t)128 * 256 * 2);
    ushort* w2_2   = (ushort*)w; w += align256((size_t)128 * 256 * 2);
    ushort* w2_3   = (ushort*)w; w += align256((size_t)128 * 128 * 2);
    float* bnA1    = (float*)w;  w += align256(128 * 4);
    float* bnB1    = (float*)w;  w += align256(128 * 4);
    float* bnA2    = (float*)w;  w += align256(128 * 4);
    float* bnB2    = (float*)w;  w += align256(128 * 4);

    hipMemsetAsync(bcnt, 0, (size_t)NBUCK * 4, stream);

    // fused prep (histogram + casts + bnprep)
    k_prep<<<PREP_GRID, 256, 0, stream>>>(ei, bcnt, x, xb,
        w_l1, w_r1, w2_1, w_l2, w_r2, w2_2, w_l3, w_r3, w2_3,
        b_l1, g1, be1, m1, v1, bnA1, bnB1,
        b_l2, g2, be2, m2, v2, bnA2, bnB2);

    // CSR build
    k_bscan<<<1, 1024, 0, stream>>>(bcnt, bstart, bcur, row_start);
    k_bin2<<<NB_BIN, 256, 0, stream>>>(ei, bcur, binned);
    k_bcsr<<<NBUCK, 256, 0, stream>>>(binned, bstart, row_start, csr_src);

    int gb = (N_NODES + 63) / 64;       // 1563
    int ab = N_NODES / 4;               // 25000

    // layer 1: aggregate-first
    k_agg_mean<<<ab, 256, 0, stream>>>(xb, row_start, csr_src, ag);
    k_gemm12<<<gb, 256, 0, stream>>>(ag, xb, w2_1, bnA1, bnB1, h1);
    // layer 2 GEMM fused with layer 3 GEMM (h2 stays in LDS)
    k_agg_mean<<<ab, 256, 0, stream>>>(h1, row_start, csr_src, ag);
    k_gemm2f<<<gb, 256, 0, stream>>>(ag, h1, w2_2, bnA2, bnB2, w2_3, b_l3, Zb, Yb);
    // layer 3 aggregation
    k_agg3<<<ab, 256, 0, stream>>>(Zb, row_start, csr_src, Yb, out);
}